// Round 1
// baseline (858.761 us; speedup 1.0000x reference)
//
#include <hip/hip_runtime.h>
#include <math.h>

// SkipGram loss: ragged embedding-bag means + log-sigmoid scoring.
// 32 lanes per bag-row; lane i owns dims [4i,4i+4) as a float4.
// One gathered table row = 32 lanes x 16B = 512B coalesced.

constexpr int NROWS = 40960;   // BATCH * 2 * WINDOW
constexpr int NEG   = 5;
constexpr int LMAX  = 4;
constexpr int D4    = 32;      // DIM/4
constexpr int MAIN_BLOCKS = NROWS * 32 / 256;  // 5120, exact

__device__ __forceinline__ float log_sigmoidf(float x) {
    // stable: min(x,0) - log1p(exp(-|x|))
    return fminf(x, 0.0f) - log1pf(__expf(-fabsf(x)));
}

__global__ __launch_bounds__(256) void skipgram_main(
    const float4* __restrict__ u_table,
    const float4* __restrict__ v_table,
    const int*  __restrict__ pos_u_idx,
    const int*  __restrict__ pos_u_len,
    const int*  __restrict__ pos_v_idx,
    const int*  __restrict__ pos_v_len,
    const int*  __restrict__ neg_v_idx,
    const int*  __restrict__ neg_v_len,
    float* __restrict__ block_sums)
{
    const int tid  = blockIdx.x * 256 + threadIdx.x;
    const int row  = tid >> 5;              // one 32-lane group per bag row
    const int lane = threadIdx.x & 31;

    // ---- embed_u (gathered once, reused for pos + 5 neg scores) ----
    float4 eu = make_float4(0.f, 0.f, 0.f, 0.f);
    {
        const int lu = pos_u_len[row];
        for (int l = 0; l < lu; ++l) {
            const int idx = pos_u_idx[row * LMAX + l];
            const float4 t = u_table[(size_t)idx * D4 + lane];
            eu.x += t.x; eu.y += t.y; eu.z += t.z; eu.w += t.w;
        }
        const float inv = 1.0f / (float)lu;
        eu.x *= inv; eu.y *= inv; eu.z *= inv; eu.w *= inv;
    }

    // ---- positive score ----
    float term;
    {
        float4 ev = make_float4(0.f, 0.f, 0.f, 0.f);
        const int lv = pos_v_len[row];
        for (int l = 0; l < lv; ++l) {
            const int idx = pos_v_idx[row * LMAX + l];
            const float4 t = v_table[(size_t)idx * D4 + lane];
            ev.x += t.x; ev.y += t.y; ev.z += t.z; ev.w += t.w;
        }
        // mean-then-dot == (dot of sums)/lv since eu already mean'd
        float s = (eu.x*ev.x + eu.y*ev.y + eu.z*ev.z + eu.w*ev.w) / (float)lv;
        #pragma unroll
        for (int off = 16; off > 0; off >>= 1) s += __shfl_xor(s, off);
        term = log_sigmoidf(s);
    }

    // ---- 5 negative scores ----
    #pragma unroll
    for (int k = 0; k < NEG; ++k) {
        const int r  = row * NEG + k;
        const int ln = neg_v_len[r];
        float4 nv = make_float4(0.f, 0.f, 0.f, 0.f);
        for (int l = 0; l < ln; ++l) {
            const int idx = neg_v_idx[r * LMAX + l];
            const float4 t = v_table[(size_t)idx * D4 + lane];
            nv.x += t.x; nv.y += t.y; nv.z += t.z; nv.w += t.w;
        }
        float ns = (eu.x*nv.x + eu.y*nv.y + eu.z*nv.z + eu.w*nv.w) / (float)ln;
        #pragma unroll
        for (int off = 16; off > 0; off >>= 1) ns += __shfl_xor(ns, off);
        term += log_sigmoidf(-ns);
    }

    // term is identical across the 32 lanes of a group (post-butterfly).
    // Sum the wave's two groups, then LDS-reduce the block's 4 waves.
    float wave_sum = term + __shfl_xor(term, 32);

    __shared__ float lds[4];
    if ((threadIdx.x & 63) == 0) lds[threadIdx.x >> 6] = wave_sum;
    __syncthreads();
    if (threadIdx.x == 0)
        block_sums[blockIdx.x] = lds[0] + lds[1] + lds[2] + lds[3];
}

__global__ __launch_bounds__(256) void skipgram_reduce(
    const float* __restrict__ block_sums,
    const int*   __restrict__ batch_size,
    float*       __restrict__ out)
{
    float s = 0.f;
    for (int i = threadIdx.x; i < MAIN_BLOCKS; i += 256) s += block_sums[i];
    #pragma unroll
    for (int off = 32; off > 0; off >>= 1) s += __shfl_xor(s, off);
    __shared__ float lds[4];
    if ((threadIdx.x & 63) == 0) lds[threadIdx.x >> 6] = s;
    __syncthreads();
    if (threadIdx.x == 0) {
        const float tot = lds[0] + lds[1] + lds[2] + lds[3];
        out[0] = -tot / (float)batch_size[0];
    }
}

extern "C" void kernel_launch(void* const* d_in, const int* in_sizes, int n_in,
                              void* d_out, int out_size, void* d_ws, size_t ws_size,
                              hipStream_t stream) {
    const float4* u_table   = (const float4*)d_in[0];
    const float4* v_table   = (const float4*)d_in[1];
    const int*    pos_u_idx = (const int*)d_in[2];
    const int*    pos_u_len = (const int*)d_in[3];
    const int*    pos_v_idx = (const int*)d_in[4];
    const int*    pos_v_len = (const int*)d_in[5];
    const int*    neg_v_idx = (const int*)d_in[6];
    const int*    neg_v_len = (const int*)d_in[7];
    const int*    batch_sz  = (const int*)d_in[8];

    float* block_sums = (float*)d_ws;   // 5120 floats, every slot written

    skipgram_main<<<MAIN_BLOCKS, 256, 0, stream>>>(
        u_table, v_table, pos_u_idx, pos_u_len, pos_v_idx, pos_v_len,
        neg_v_idx, neg_v_len, block_sums);

    skipgram_reduce<<<1, 256, 0, stream>>>(block_sums, batch_sz, (float*)d_out);
}